// Round 3
// baseline (131.055 us; speedup 1.0000x reference)
//
#include <hip/hip_runtime.h>
#include <hip/hip_bf16.h>

// SupConLoss, B=8192, D=128, T=0.1. Output: single fp32 scalar.
//
// Pipeline (3 launches):
//   1) supcon_convert — per-wave dtype detection (fp32 vs bf16 feats, i64 vs
//      i32 labels) folded in; canonicalizes features -> bf16 ws copy (RTNE),
//      labels -> int32 ws copy; zeroes the final-accumulator ws slots.
//   2) supcon_main    — fused bf16-MFMA GEMM (F·F^T) + masked exp/pos
//      accumulation. NO LDS staging, NO in-loop barriers: the 2 MB bf16
//      feature matrix is L2-resident (4 MB/XCD), so A- and B-fragments are
//      read DIRECTLY from global (Common-mistake #7: don't stage L2-fit
//      data; m233: stage+barrier is ~72% of a 2-phase loop). Raw diagonal
//      dot s_ii captured to ws once per row. Per-(chunk,row) e/p partials.
//   3) supcon_reduce  — row partials -> scalar loss. n_i from an exact label
//      histogram (n_i = count[label_i] - 1, integer-exact). Diagonal terms
//      subtracted exactly (bitwise-identical exp2). Last-block-atomic
//      finalization (ticket zeroed by convert -> graph-replay safe).
//
// Math: with ANY fixed shift M (instead of per-row max), per row i:
//   mean_log_prob_i = 10*p_i/n_i - M - log(sum_{j!=i} exp(s_ij - M))
// identical to the reference (shift cancels). M=10.5 >= max s_ij for
// unit-norm features. exp folded to exp2: exp(10a-10.5) = exp2(a*C1 + C2).
// Diagonal removal: e_corr = e_full - exp2(fma(d,C1,C2)) (same instruction,
// same input -> bitwise-identical term), p_corr = p_full - d.
//
// History: r1: __launch_bounds__(256,4) forced VGPR=64 -> spill, FETCH 9.7MB
// -> 646MB, 46->215us. Never clamp below the live set. r2: NC=16 + n_acc
// removal: main ~46 -> ~38us; profile shows a fixed 41us / 268MB harness
// workspace-poison fill in the timed region (uncontrollable floor).

#define BB 8192
#define DD 128
#define NC 32                // column chunks (grid.x): 2048 blocks
#define COLCHUNK (BB / NC)   // 256 cols per WG
#define ITERS (COLCHUNK / 128)
#define TEMP_INV 10.0f
#define MSHIFT 10.5f
#define C1F 14.426950408889634f    /* 10*log2(e)    */
#define C2F -15.148297929334116f   /* -10.5*log2(e) */

typedef __bf16 bf16x8 __attribute__((ext_vector_type(8)));
typedef float floatx4 __attribute__((ext_vector_type(4)));

__device__ inline float fast_exp2(float x) {
#if __has_builtin(__builtin_amdgcn_exp2f)
    return __builtin_amdgcn_exp2f(x);
#else
    return exp2f(x);
#endif
}

__device__ inline unsigned short f2bf(float f) {           // RTNE fp32->bf16
    unsigned u = __float_as_uint(f);
    return (unsigned short)((u + 0x7FFFu + ((u >> 16) & 1u)) >> 16);
}

// ---- 1) canonicalize (+ detect + zero finals) ----
__global__ __launch_bounds__(256) void supcon_convert(
    const void* __restrict__ fin, const void* __restrict__ lin,
    unsigned short* __restrict__ fbf, int* __restrict__ lab,
    float* __restrict__ accbuf)
{
    // Per-wave dtype detection: every wave reads the same 128-short feature
    // header and 128-int label header, butterfly-reduces across its own 64
    // lanes -> every thread holds the verdict, no LDS/sync needed.
    int lane = threadIdx.x & 63;
    unsigned ue = ((unsigned)((const unsigned short*)fin)[2 * lane]) << 16;
    float fe = __uint_as_float(ue);
    float ve = fe * fe;
    int odd_or = ((const int*)lin)[2 * lane + 1];
#pragma unroll
    for (int m = 1; m < 64; m <<= 1) {
        ve += __shfl_xor(ve, m, 64);
        odd_or |= __shfl_xor(odd_or, m, 64);
    }
    // true bf16 unit rows: sum sq of 64 even slots of row 0 is ~0.5.
    bool f_bf16 = (ve > 0.05f) && (ve < 4.0f);   // NaN-safe: NaN -> false
    bool l_i64  = (odd_or == 0);

    int gid = blockIdx.x * 256 + threadIdx.x;    // 262144 threads x 4 elements
    if (!f_bf16) {
        float4 v = ((const float4*)fin)[gid];
        ushort4 o;
        o.x = f2bf(v.x); o.y = f2bf(v.y); o.z = f2bf(v.z); o.w = f2bf(v.w);
        ((ushort4*)fbf)[gid] = o;
    } else {
        ((ushort4*)fbf)[gid] = ((const ushort4*)fin)[gid];
    }
    if (blockIdx.x < 32) {
        int li = blockIdx.x * 256 + threadIdx.x;
        const int* L = (const int*)lin;
        lab[li] = l_i64 ? L[2 * li] : L[li];
    }
    if (blockIdx.x == 0 && threadIdx.x == 0) {   // zero last-block finals
        accbuf[0] = 0.0f;                        // loss sum
        accbuf[1] = 0.0f;                        // valid count
        ((unsigned*)accbuf)[2] = 0u;             // ticket
    }
}

// ---- 2) fused GEMM + masked softmax partials (LDS-free, barrier-free) ----
__global__ __launch_bounds__(256, 2) void supcon_main(
    const unsigned short* __restrict__ Fb, const int* __restrict__ labels,
    float* __restrict__ e_part, float* __restrict__ p_part,
    float* __restrict__ diag)
{
    __shared__ float red[2][128][2];              // only LDS: final cross-wave sum

    const int tid  = threadIdx.x;
    const int lane = tid & 63;
    const int wid  = tid >> 6;
    const int wrow = wid >> 1;
    const int wcol = wid & 1;
    const int quad = lane >> 4;
    const int l16  = lane & 15;

    const int chunk   = blockIdx.x;
    const int rowbase = blockIdx.y * 128;
    const int colchunkbase = chunk * COLCHUNK;

    const unsigned char* Fbc = (const unsigned char*)Fb;

    // A fragments directly from global (L2-resident). Element mapping is the
    // same as the old swizzled-LDS path: A[m=l16][k-chunk g = k*4+quad] at
    // row*256 + g*16 bytes -> values bit-identical to before.
    bf16x8 afrag[4][4];
#pragma unroll
    for (int ti = 0; ti < 4; ++ti) {
        int row = rowbase + wrow * 64 + ti * 16 + l16;
        const unsigned char* gA = Fbc + (size_t)row * 256 + quad * 16;
#pragma unroll
        for (int k = 0; k < 4; ++k)
            afrag[ti][k] = *(const bf16x8*)(gA + k * 64);
    }

    int lab_row[16];
#pragma unroll
    for (int ti = 0; ti < 4; ++ti)
#pragma unroll
        for (int r = 0; r < 4; ++r)
            lab_row[ti * 4 + r] = labels[rowbase + wrow * 64 + ti * 16 + quad * 4 + r];

    float e_acc[16], p_acc[16];
#pragma unroll
    for (int i = 0; i < 16; ++i) { e_acc[i] = 0.0f; p_acc[i] = 0.0f; }

    for (int it = 0; it < ITERS; ++it) {
        int colbase = colchunkbase + it * 128;
#pragma unroll
        for (int tj = 0; tj < 4; ++tj) {
            int coll = colbase + wcol * 64 + tj * 16 + l16;   // absolute col
            const unsigned char* gB = Fbc + (size_t)coll * 256 + quad * 16;
            bf16x8 bfrag[4];
#pragma unroll
            for (int k = 0; k < 4; ++k)
                bfrag[k] = *(const bf16x8*)(gB + k * 64);

            floatx4 acc[4];
#pragma unroll
            for (int ti = 0; ti < 4; ++ti) acc[ti] = (floatx4){0.f, 0.f, 0.f, 0.f};
#pragma unroll
            for (int k = 0; k < 4; ++k)
#pragma unroll
                for (int ti = 0; ti < 4; ++ti)
                    acc[ti] = __builtin_amdgcn_mfma_f32_16x16x32_bf16(
                        afrag[ti][k], bfrag[k], acc[ti], 0, 0, 0);

            // Diagonal capture: wave-uniform, rare (once per 64 diag cols).
            // Static indexing of acc (rule: no runtime ext_vector index).
            {
                int ctb = colbase + wcol * 64 + tj * 16;
                unsigned u = (unsigned)(ctb - (rowbase + wrow * 64));
                if (u < 64u) {
#pragma unroll
                    for (int ti2 = 0; ti2 < 4; ++ti2) {
                        if (u == (unsigned)(ti2 * 16)) {
#pragma unroll
                            for (int r = 0; r < 4; ++r)
                                if (l16 == quad * 4 + r)
                                    diag[ctb + l16] = acc[ti2][r];
                        }
                    }
                }
            }

            int lab_c = labels[coll];
#pragma unroll
            for (int ti = 0; ti < 4; ++ti) {
#pragma unroll
                for (int r = 0; r < 4; ++r) {
                    // C/D: D[row=quad*4+r][col=l16] (m89/m91 verified)
                    // 6 VALU/elem: fma, exp2, add, cmp, cndmask, fma.
                    int i = ti * 4 + r;
                    float a  = acc[ti][r];                       // raw dot
                    float ex = fast_exp2(__builtin_fmaf(a, C1F, C2F));
                    e_acc[i] += ex;
                    float peq = (lab_c == lab_row[i]) ? 1.0f : 0.0f;
                    p_acc[i] = __builtin_fmaf(peq, a, p_acc[i]); // raw-dot units
                }
            }
        }
    }

    // reduce across 16 column-lanes (xor over lane bits 0..3)
#pragma unroll
    for (int i = 0; i < 16; ++i) {
        float e = e_acc[i], p = p_acc[i];
#pragma unroll
        for (int m = 1; m < 16; m <<= 1) {
            e += __shfl_xor(e, m, 64);
            p += __shfl_xor(p, m, 64);
        }
        if (l16 == 0) {
            int row_local = wrow * 64 + (i >> 2) * 16 + quad * 4 + (i & 3);
            red[0][row_local][wcol] = e;
            red[1][row_local][wcol] = p;
        }
    }
    __syncthreads();

    if (tid < 128) {
        size_t idx = (size_t)chunk * BB + (rowbase + tid);
        e_part[idx] = red[0][tid][0] + red[0][tid][1];
        p_part[idx] = red[1][tid][0] + red[1][tid][1];
    }
}

// ---- 3) row partials -> scalar loss (histogram n + last-block atomic) ----
__global__ __launch_bounds__(256) void supcon_reduce(
    const float* __restrict__ e_part, const float* __restrict__ p_part,
    const int* __restrict__ labels, const float* __restrict__ diag,
    float* __restrict__ accbuf, float* __restrict__ out)
{
    // Exact per-class counts over the whole batch (labels in [0,100)).
    __shared__ int cnt[128];
    if (threadIdx.x < 128) cnt[threadIdx.x] = 0;
    __syncthreads();
    for (int i = threadIdx.x; i < BB; i += 256)
        atomicAdd(&cnt[labels[i]], 1);
    __syncthreads();

    int row = blockIdx.x * 256 + threadIdx.x;    // grid 32
    float e = 0.f, p = 0.f;
#pragma unroll
    for (int c = 0; c < NC; ++c) {
        size_t idx = (size_t)c * BB + row;
        e += e_part[idx]; p += p_part[idx];
    }
    // exact diagonal removal (same exp2 instruction on same input as main)
    float d = diag[row];
    e -= fast_exp2(__builtin_fmaf(d, C1F, C2F));
    p -= d;
    int n_i = cnt[labels[row]] - 1;              // integer-exact positive count

    float contrib = 0.f, vld = 0.f;
    if (n_i > 0) {
        vld = 1.0f;
        contrib = -(p * TEMP_INV / (float)n_i - MSHIFT - logf(e));
    }
#pragma unroll
    for (int m = 1; m < 64; m <<= 1) {
        contrib += __shfl_xor(contrib, m, 64);
        vld     += __shfl_xor(vld, m, 64);
    }
    __shared__ float rl[4], rv[4];
    int lane = threadIdx.x & 63, w = threadIdx.x >> 6;
    if (lane == 0) { rl[w] = contrib; rv[w] = vld; }
    __syncthreads();
    if (threadIdx.x == 0) {
        float L = rl[0] + rl[1] + rl[2] + rl[3];
        float V = rv[0] + rv[1] + rv[2] + rv[3];
        atomicAdd(&accbuf[0], L);
        atomicAdd(&accbuf[1], V);
        __threadfence();
        unsigned t = atomicAdd((unsigned*)accbuf + 2, 1u);
        if (t == 31u) {                      // last block: all adds fenced+done
            float Ls = atomicAdd(&accbuf[0], 0.0f);
            float Vs = atomicAdd(&accbuf[1], 0.0f);
            out[0] = (Vs > 0.5f) ? (Ls / Vs) : 0.0f;
        }
    }
}

extern "C" void kernel_launch(void* const* d_in, const int* in_sizes, int n_in,
                              void* d_out, int out_size, void* d_ws, size_t ws_size,
                              hipStream_t stream)
{
    const void* Fin = d_in[0];
    const void* Lin = d_in[1];

    // ws layout (~4.2 MB)
    unsigned short* fbf = (unsigned short*)d_ws;                          // 2 MB bf16 copy
    int*   lab      = (int*)((char*)d_ws + (size_t)BB * DD * 2);          // 32 KB
    float* e_part   = (float*)((char*)lab + (size_t)BB * 4);              // NC*B floats
    float* p_part   = e_part + (size_t)NC * BB;
    float* diag     = p_part + (size_t)NC * BB;                           // B floats
    float* accbuf   = diag + BB;                                          // 3 slots

    supcon_convert<<<BB * DD / 4 / 256, 256, 0, stream>>>(Fin, Lin, fbf, lab, accbuf);

    dim3 grid(NC, BB / 128);
    supcon_main<<<grid, 256, 0, stream>>>(fbf, lab, e_part, p_part, diag);

    supcon_reduce<<<32, 256, 0, stream>>>(e_part, p_part, lab, diag, accbuf, (float*)d_out);
}

// Round 4
// 97.236 us; speedup vs baseline: 1.3478x; 1.3478x over previous
//
#include <hip/hip_runtime.h>
#include <hip/hip_bf16.h>

// SupConLoss, B=8192, D=128, T=0.1. Output: single fp32 scalar.
//
// Pipeline (3 launches):
//   1) supcon_convert — per-wave dtype detection (fp32 vs bf16 feats, i64 vs
//      i32 labels) folded in; canonicalizes features -> bf16 ws copy (RTNE),
//      labels -> int32 ws copy; zeroes the final-accumulator ws slots.
//   2) supcon_main    — fused bf16-MFMA GEMM (F·F^T) + masked exp/pos
//      accumulation. LDS double-buffered B tiles staged via
//      global_load_lds(16B) with the XOR swizzle applied on the GLOBAL
//      source address (linear LDS dest + inverse-swz source + swz read:
//      same involution -> bit-identical to the old ds_write path).
//      T3 minimum 2-phase pipeline: issue next tile's stage BEFORE
//      computing the current tile; one drain+barrier per tile, so the
//      ~500cy load latency hides under ~2000cy of MFMA+epilogue.
//      Raw diagonal dot s_ii captured to ws once per row.
//   3) supcon_reduce  — row partials -> scalar loss. n_i from an exact label
//      histogram (n_i = count[label_i] - 1, integer-exact). Diagonal terms
//      subtracted exactly (bitwise-identical exp2). Last-block-atomic
//      finalization (ticket zeroed by convert -> graph-replay safe).
//
// Math: with ANY fixed shift M (instead of per-row max), per row i:
//   mean_log_prob_i = 10*p_i/n_i - M - log(sum_{j!=i} exp(s_ij - M))
// identical to the reference (shift cancels). M=10.5 >= max s_ij for
// unit-norm features. exp folded to exp2: exp(10a-10.5) = exp2(a*C1 + C2).
// Diagonal removal: e_corr = e_full - exp2(fma(d,C1,C2)) (same instruction,
// same input -> bitwise-identical term), p_corr = p_full - d.
//
// History:
//  r1: __launch_bounds__(256,4) forced VGPR=64 -> spill, FETCH 9.7->646MB,
//      46->215us. Never clamp below the live set.
//  r2: NC=16 + n_acc removal: main ~46 -> ~38us. Fixed 41us/268MB harness
//      workspace-poison fill in the timed region (uncontrollable floor).
//  r3: removed LDS staging (direct L2 reads): main 38 -> 68.7us, all utils
//      low. Latency-bound serial load->mfma chain; L2-residency removes the
//      BW cost of staging, not the latency cost. LDS staging restored.

#define BB 8192
#define DD 128
#define NC 8                 // column chunks (grid.x): 512 blocks = 2/CU exact
#define COLCHUNK (BB / NC)   // 1024 cols per WG
#define ITERS (COLCHUNK / 128)
#define TEMP_INV 10.0f
#define MSHIFT 10.5f
#define C1F 14.426950408889634f    /* 10*log2(e)    */
#define C2F -15.148297929334116f   /* -10.5*log2(e) */

typedef __bf16 bf16x8 __attribute__((ext_vector_type(8)));
typedef float floatx4 __attribute__((ext_vector_type(4)));

__device__ inline float fast_exp2(float x) {
#if __has_builtin(__builtin_amdgcn_exp2f)
    return __builtin_amdgcn_exp2f(x);
#else
    return exp2f(x);
#endif
}

__device__ inline unsigned short f2bf(float f) {           // RTNE fp32->bf16
    unsigned u = __float_as_uint(f);
    return (unsigned short)((u + 0x7FFFu + ((u >> 16) & 1u)) >> 16);
}

__device__ inline void gload_lds16(const void* g, void* l) {
    __builtin_amdgcn_global_load_lds(
        (const __attribute__((address_space(1))) void*)g,
        (__attribute__((address_space(3))) void*)l, 16, 0, 0);
}

// ---- 1) canonicalize (+ detect + zero finals) ----
__global__ __launch_bounds__(256) void supcon_convert(
    const void* __restrict__ fin, const void* __restrict__ lin,
    unsigned short* __restrict__ fbf, int* __restrict__ lab,
    float* __restrict__ accbuf)
{
    // Per-wave dtype detection: every wave reads the same 128-short feature
    // header and 128-int label header, butterfly-reduces across its own 64
    // lanes -> every thread holds the verdict, no LDS/sync needed.
    int lane = threadIdx.x & 63;
    unsigned ue = ((unsigned)((const unsigned short*)fin)[2 * lane]) << 16;
    float fe = __uint_as_float(ue);
    float ve = fe * fe;
    int odd_or = ((const int*)lin)[2 * lane + 1];
#pragma unroll
    for (int m = 1; m < 64; m <<= 1) {
        ve += __shfl_xor(ve, m, 64);
        odd_or |= __shfl_xor(odd_or, m, 64);
    }
    // true bf16 unit rows: sum sq of 64 even slots of row 0 is ~0.5.
    bool f_bf16 = (ve > 0.05f) && (ve < 4.0f);   // NaN-safe: NaN -> false
    bool l_i64  = (odd_or == 0);

    int gid = blockIdx.x * 256 + threadIdx.x;    // 262144 threads x 4 elements
    if (!f_bf16) {
        float4 v = ((const float4*)fin)[gid];
        ushort4 o;
        o.x = f2bf(v.x); o.y = f2bf(v.y); o.z = f2bf(v.z); o.w = f2bf(v.w);
        ((ushort4*)fbf)[gid] = o;
    } else {
        ((ushort4*)fbf)[gid] = ((const ushort4*)fin)[gid];
    }
    if (blockIdx.x < 32) {
        int li = blockIdx.x * 256 + threadIdx.x;
        const int* L = (const int*)lin;
        lab[li] = l_i64 ? L[2 * li] : L[li];
    }
    if (blockIdx.x == 0 && threadIdx.x == 0) {   // zero last-block finals
        accbuf[0] = 0.0f;                        // loss sum
        accbuf[1] = 0.0f;                        // valid count
        ((unsigned*)accbuf)[2] = 0u;             // ticket
    }
}

// Stage one 128-col B tile (32KB) into ldsB[bsel] via global_load_lds.
// LDS dest is LINEAR (wave-uniform base + lane*16, hardware rule); the XOR
// swizzle is applied to the SOURCE address. Dest slot d of row r receives
// source chunk d^(r&15); the swizzled ds_read of chunk g at slot g^(r&15)
// therefore returns chunk g — identical values to the old ds_write path.
#define STAGE_B(itx, bsel)                                                   \
    {                                                                        \
        const unsigned char* gB =                                            \
            Fbc + (size_t)(colchunkbase + (itx) * 128) * 256;                \
        unsigned char* lb = &ldsB[bsel][0];                                  \
        _Pragma("unroll")                                                    \
        for (int r = 0; r < 8; ++r) {                                        \
            int off = r * 4096 + wid * 1024 + lane * 16;                     \
            int row = off >> 8;                                              \
            int g   = (off >> 4) & 15;                                       \
            int gs  = g ^ (row & 15);                                        \
            gload_lds16(gB + row * 256 + gs * 16,                            \
                        lb + r * 4096 + wid * 1024);                         \
        }                                                                    \
    }

// ---- 2) fused GEMM + masked softmax partials (2-phase pipelined) ----
__global__ __launch_bounds__(256, 2) void supcon_main(
    const unsigned short* __restrict__ Fb, const int* __restrict__ labels,
    float* __restrict__ e_part, float* __restrict__ p_part,
    float* __restrict__ diag)
{
    __shared__ unsigned char ldsB[2][32768];      // double-buffered B tiles
    __shared__ float red[2][128][2];

    const int tid  = threadIdx.x;
    const int lane = tid & 63;
    const int wid  = tid >> 6;
    const int wrow = wid >> 1;
    const int wcol = wid & 1;
    const int quad = lane >> 4;
    const int l16  = lane & 15;

    const int chunk   = blockIdx.x;
    const int rowbase = blockIdx.y * 128;
    const int colchunkbase = chunk * COLCHUNK;

    const unsigned char* Fbc = (const unsigned char*)Fb;

    // Prologue: stage tile 0, then load A-frags direct from global (L2) —
    // the A loads' latency overlaps the tile-0 staging in flight.
    STAGE_B(0, 0);

    // A fragments directly from global (L2-resident, once per block).
    bf16x8 afrag[4][4];
#pragma unroll
    for (int ti = 0; ti < 4; ++ti) {
        int row = rowbase + wrow * 64 + ti * 16 + l16;
        const unsigned char* gA = Fbc + (size_t)row * 256 + quad * 16;
#pragma unroll
        for (int k = 0; k < 4; ++k)
            afrag[ti][k] = *(const bf16x8*)(gA + k * 64);
    }

    int lab_row[16];
#pragma unroll
    for (int ti = 0; ti < 4; ++ti)
#pragma unroll
        for (int r = 0; r < 4; ++r)
            lab_row[ti * 4 + r] = labels[rowbase + wrow * 64 + ti * 16 + quad * 4 + r];

    float e_acc[16], p_acc[16];
#pragma unroll
    for (int i = 0; i < 16; ++i) { e_acc[i] = 0.0f; p_acc[i] = 0.0f; }

    __syncthreads();   // drains tile-0 staging (vmcnt(0)) + barrier

    int cur = 0;
    for (int it = 0; it < ITERS; ++it) {
        // Issue next tile's stage FIRST: its latency hides under this
        // tile's MFMA+epilogue (~2000cy >> ~500cy load latency).
        if (it + 1 < ITERS) STAGE_B(it + 1, cur ^ 1);

        int colbase = colchunkbase + it * 128;
        const unsigned char* lb = &ldsB[cur][0];

#pragma unroll
        for (int tj = 0; tj < 4; ++tj) {
            int coll = wcol * 64 + tj * 16 + l16;   // B[n=l16][k=quad*8+j]
            bf16x8 bfrag[4];
#pragma unroll
            for (int k = 0; k < 4; ++k) {
                int g  = k * 4 + quad;
                int gs = g ^ (coll & 15);
                bfrag[k] = *(const bf16x8*)(lb + coll * 256 + gs * 16);
            }
            floatx4 acc[4];
#pragma unroll
            for (int ti = 0; ti < 4; ++ti) acc[ti] = (floatx4){0.f, 0.f, 0.f, 0.f};
#pragma unroll
            for (int k = 0; k < 4; ++k)
#pragma unroll
                for (int ti = 0; ti < 4; ++ti)
                    acc[ti] = __builtin_amdgcn_mfma_f32_16x16x32_bf16(
                        afrag[ti][k], bfrag[k], acc[ti], 0, 0, 0);

            // Diagonal capture: wave-uniform, rare (once per 64 diag cols).
            // Static indexing of acc (rule: no runtime ext_vector index).
            {
                int ctb = colbase + wcol * 64 + tj * 16;
                unsigned u = (unsigned)(ctb - (rowbase + wrow * 64));
                if (u < 64u) {
#pragma unroll
                    for (int ti2 = 0; ti2 < 4; ++ti2) {
                        if (u == (unsigned)(ti2 * 16)) {
#pragma unroll
                            for (int r = 0; r < 4; ++r)
                                if (l16 == quad * 4 + r)
                                    diag[ctb + l16] = acc[ti2][r];
                        }
                    }
                }
            }

            int lab_c = labels[colbase + coll];
#pragma unroll
            for (int ti = 0; ti < 4; ++ti) {
#pragma unroll
                for (int r = 0; r < 4; ++r) {
                    // C/D: D[row=quad*4+r][col=l16] (m89/m91 verified)
                    // 6 VALU/elem: fma, exp2, add, cmp, cndmask, fma.
                    int i = ti * 4 + r;
                    float a  = acc[ti][r];                       // raw dot
                    float ex = fast_exp2(__builtin_fmaf(a, C1F, C2F));
                    e_acc[i] += ex;
                    float peq = (lab_c == lab_row[i]) ? 1.0f : 0.0f;
                    p_acc[i] = __builtin_fmaf(peq, a, p_acc[i]); // raw-dot units
                }
            }
        }
        __syncthreads();   // drain next-tile loads + all waves done reading cur
        cur ^= 1;
    }

    // reduce across 16 column-lanes (xor over lane bits 0..3)
#pragma unroll
    for (int i = 0; i < 16; ++i) {
        float e = e_acc[i], p = p_acc[i];
#pragma unroll
        for (int m = 1; m < 16; m <<= 1) {
            e += __shfl_xor(e, m, 64);
            p += __shfl_xor(p, m, 64);
        }
        if (l16 == 0) {
            int row_local = wrow * 64 + (i >> 2) * 16 + quad * 4 + (i & 3);
            red[0][row_local][wcol] = e;
            red[1][row_local][wcol] = p;
        }
    }
    __syncthreads();

    if (tid < 128) {
        size_t idx = (size_t)chunk * BB + (rowbase + tid);
        e_part[idx] = red[0][tid][0] + red[0][tid][1];
        p_part[idx] = red[1][tid][0] + red[1][tid][1];
    }
}

// ---- 3) row partials -> scalar loss (histogram n + last-block atomic) ----
__global__ __launch_bounds__(256) void supcon_reduce(
    const float* __restrict__ e_part, const float* __restrict__ p_part,
    const int* __restrict__ labels, const float* __restrict__ diag,
    float* __restrict__ accbuf, float* __restrict__ out)
{
    // Exact per-class counts over the whole batch (labels in [0,100)).
    __shared__ int cnt[128];
    if (threadIdx.x < 128) cnt[threadIdx.x] = 0;
    __syncthreads();
    for (int i = threadIdx.x; i < BB; i += 256)
        atomicAdd(&cnt[labels[i]], 1);
    __syncthreads();

    int row = blockIdx.x * 256 + threadIdx.x;    // grid 32
    float e = 0.f, p = 0.f;
#pragma unroll
    for (int c = 0; c < NC; ++c) {
        size_t idx = (size_t)c * BB + row;
        e += e_part[idx]; p += p_part[idx];
    }
    // exact diagonal removal (same exp2 instruction on same input as main)
    float d = diag[row];
    e -= fast_exp2(__builtin_fmaf(d, C1F, C2F));
    p -= d;
    int n_i = cnt[labels[row]] - 1;              // integer-exact positive count

    float contrib = 0.f, vld = 0.f;
    if (n_i > 0) {
        vld = 1.0f;
        contrib = -(p * TEMP_INV / (float)n_i - MSHIFT - logf(e));
    }
#pragma unroll
    for (int m = 1; m < 64; m <<= 1) {
        contrib += __shfl_xor(contrib, m, 64);
        vld     += __shfl_xor(vld, m, 64);
    }
    __shared__ float rl[4], rv[4];
    int lane = threadIdx.x & 63, w = threadIdx.x >> 6;
    if (lane == 0) { rl[w] = contrib; rv[w] = vld; }
    __syncthreads();
    if (threadIdx.x == 0) {
        float L = rl[0] + rl[1] + rl[2] + rl[3];
        float V = rv[0] + rv[1] + rv[2] + rv[3];
        atomicAdd(&accbuf[0], L);
        atomicAdd(&accbuf[1], V);
        __threadfence();
        unsigned t = atomicAdd((unsigned*)accbuf + 2, 1u);
        if (t == 31u) {                      // last block: all adds fenced+done
            float Ls = atomicAdd(&accbuf[0], 0.0f);
            float Vs = atomicAdd(&accbuf[1], 0.0f);
            out[0] = (Vs > 0.5f) ? (Ls / Vs) : 0.0f;
        }
    }
}

extern "C" void kernel_launch(void* const* d_in, const int* in_sizes, int n_in,
                              void* d_out, int out_size, void* d_ws, size_t ws_size,
                              hipStream_t stream)
{
    const void* Fin = d_in[0];
    const void* Lin = d_in[1];

    // ws layout (~2.6 MB)
    unsigned short* fbf = (unsigned short*)d_ws;                          // 2 MB bf16 copy
    int*   lab      = (int*)((char*)d_ws + (size_t)BB * DD * 2);          // 32 KB
    float* e_part   = (float*)((char*)lab + (size_t)BB * 4);              // NC*B floats
    float* p_part   = e_part + (size_t)NC * BB;
    float* diag     = p_part + (size_t)NC * BB;                           // B floats
    float* accbuf   = diag + BB;                                          // 3 slots

    supcon_convert<<<BB * DD / 4 / 256, 256, 0, stream>>>(Fin, Lin, fbf, lab, accbuf);

    dim3 grid(NC, BB / 128);
    supcon_main<<<grid, 256, 0, stream>>>(fbf, lab, e_part, p_part, diag);

    supcon_reduce<<<32, 256, 0, stream>>>(e_part, p_part, lab, diag, accbuf, (float*)d_out);
}